// Round 20
// baseline (65.497 us; speedup 1.0000x reference)
//
#include <hip/hip_runtime.h>
#include <math.h>

#define B_ 4
#define H_ 12
#define N_ 1025
#define D_ 64
#define HID_ 32
#define TBL_ 3969            // (2*32-1)^2
#define NQT 17               // 64-row tiles in both q and k
#define NBLK (B_ * H_ * NQT) // 816
#define NBLK2 (NBLK * 2)     // 1632 k-split blocks, divisible by 8
#define LOG2E 1.44269504f
#define THR_ 12.0f           // defer-max threshold (log2 domain)

typedef _Float16 half8 __attribute__((ext_vector_type(8)));
typedef __fp16 fp16x2 __attribute__((ext_vector_type(2)));
typedef float f32x4 __attribute__((ext_vector_type(4)));
typedef float f32x4u __attribute__((ext_vector_type(4), aligned(4)));  // 4B-aligned float4

#if defined(__has_builtin)
#if __has_builtin(__builtin_amdgcn_exp2f)
#define EX2 __builtin_amdgcn_exp2f
#else
#define EX2 exp2f
#endif
#else
#define EX2 exp2f
#endif

// ws layout (bytes):
//   akT  @ 0        : 48*1088*4 = 208896    (pad for btR underrun)
//   btR  @ 208896   : 12*3969*4 = 190512    (REVERSED bias table)
//   Kf   @ 399408   : 6684672
//   Vf   @ 7084080  : 6684672               (end 13768752)
//   Opart@ 13768768 : 96*1088*64*2 = 13369344  (normalized f16 partials, k-split)
//   ml   @ 27138112 : 96*1088*8 = 835584       (float2 (m,l) per partial row)
//   total needed for k-split: 27973696
#define AKT_OFF 0
#define BTR_OFF 208896
#define KF_OFF 399408
#define VF_OFF 7084080
#define OP_OFF 13768768
#define ML_OFF 27138112
#define WS_NEED 27973696ull

__device__ __forceinline__ void stage16(const _Float16* gsrc, _Float16* ldst) {
    __builtin_amdgcn_global_load_lds(
        (const __attribute__((address_space(1))) void*)gsrc,
        (__attribute__((address_space(3))) void*)ldst, 16, 0, 0);
}

// ---------------- prep: K/V -> f16 fragment-order tiles (both via LDS, coalesced
// global reads), akT, btR (reversed). Same as round 18.
__global__ __launch_bounds__(256) void prep(
    const float* __restrict__ K, const float* __restrict__ V,
    const float* __restrict__ MU, const float* __restrict__ GAMMA,
    const float* __restrict__ rel, const float* __restrict__ w1,
    const float* __restrict__ b1, const float* __restrict__ w2,
    _Float16* __restrict__ Kf, _Float16* __restrict__ Vf,
    float* __restrict__ akT, float* __restrict__ btR) {
    const int bid = blockIdx.x;
    const int tid = threadIdx.x;
    if (bid < NBLK) {
        __shared__ float Vls[64 * 65];
        __shared__ __align__(16) float Kls[64 * 64];
        const int bh = bid / NQT, kt = bid % NQT;
        const size_t base = (size_t)bh * (N_ * D_);
        const int k0 = kt * 64;
#pragma unroll
        for (int it = 0; it < 4; ++it) {
            const int idx = it * 256 + tid;
            const int kr = idx >> 4, c4 = (idx & 15) << 2;
            const int kg = k0 + kr;
            float4 v4 = make_float4(0, 0, 0, 0), k4 = v4;
            if (kg < N_) {
                v4 = *(const float4*)(V + base + (size_t)kg * D_ + c4);
                k4 = *(const float4*)(K + base + (size_t)kg * D_ + c4);
            }
            Vls[(c4 + 0) * 65 + kr] = v4.x;
            Vls[(c4 + 1) * 65 + kr] = v4.y;
            Vls[(c4 + 2) * 65 + kr] = v4.z;
            Vls[(c4 + 3) * 65 + kr] = v4.w;
            const int gi = (c4 >> 2) ^ (kr & 15);
            *(float4*)&Kls[kr * 64 + (gi << 2)] = k4;
        }
        if (tid < 64) {
            const int kk = k0 + tid;
            const int h = bh % H_;
            const float sgl = LOG2E / (1.f + __expf(-GAMMA[h]));
            float a = 0.f;
            if (kk >= 1 && kk < N_) a = sgl * MU[((size_t)bh * 2 + 1) * N_ + kk];
            akT[bh * 1088 + kk] = a;
        }
        __syncthreads();
        const int lane = tid & 63, lq = lane & 15, g = lane >> 4;
        const int fbh = tid >> 6;
        const size_t tb = (size_t)(bh * NQT + kt) * 4096;
#pragma unroll
        for (int x = 0; x < 2; ++x) {
            const int fb = fbh + x * 4;
            {
                const int kh = fb >> 2, dg = fb & 3;
                const float* vp = &Vls[(dg * 16 + lq) * 65 + kh * 32 + g * 8];
                half8 v8;
#pragma unroll
                for (int j = 0; j < 8; ++j) v8[j] = (_Float16)vp[j];
                *(half8*)&Vf[tb + fb * 512 + lane * 8] = v8;
            }
            {
                const int row = (fb >> 1) * 16 + lq;
                const int col = (fb & 1) * 32 + g * 8;
                const int ga = ((col >> 2) + 0) ^ (row & 15);
                const int gb = ((col >> 2) + 1) ^ (row & 15);
                f32x4 a = *(const f32x4*)&Kls[row * 64 + (ga << 2)];
                f32x4 b = *(const f32x4*)&Kls[row * 64 + (gb << 2)];
                half8 k8;
                k8[0] = (_Float16)a[0]; k8[1] = (_Float16)a[1];
                k8[2] = (_Float16)a[2]; k8[3] = (_Float16)a[3];
                k8[4] = (_Float16)b[0]; k8[5] = (_Float16)b[1];
                k8[6] = (_Float16)b[2]; k8[7] = (_Float16)b[3];
                *(half8*)&Kf[tb + fb * 512 + lane * 8] = k8;
            }
        }
    } else {
        const int i = (bid - NBLK) * 256 + tid;
        if (i < TBL_) {
            const float x0 = rel[2 * i + 0], x1 = rel[2 * i + 1];
            float acc[H_];
#pragma unroll
            for (int h = 0; h < H_; ++h) acc[h] = 0.f;
#pragma unroll
            for (int j = 0; j < HID_; ++j) {
                float t = fmaf(x0, w1[j], fmaf(x1, w1[HID_ + j], b1[j]));
                float gl = 0.5f * t * (1.f + erff(t * 0.7071067811865475f));
#pragma unroll
                for (int h = 0; h < H_; ++h) acc[h] = fmaf(gl, w2[j * H_ + h], acc[h]);
            }
#pragma unroll
            for (int h = 0; h < H_; ++h) btR[h * TBL_ + (TBL_ - 1 - i)] = acc[h];
        }
    }
}

// ---------------- fused flash attention. SPLIT=1: 1632 blocks, each does half the
// k-range and writes a normalized f16 partial + (m,l); SPLIT=0: single-pass r18.
// P tile aliases dead Ks[buf] (32KB LDS -> 5 blocks/CU residency cap).
template <int SPLIT>
__global__ __launch_bounds__(256, 4) void flex_attn(
    const float* __restrict__ Q, const _Float16* __restrict__ Kf,
    const _Float16* __restrict__ Vf, const float* __restrict__ MU,
    const float* __restrict__ GAMMA, const char* __restrict__ btb,
    const float* __restrict__ akT, _Float16* __restrict__ Opart,
    float* __restrict__ mlb, float* __restrict__ OUT) {
    __shared__ __align__(16) _Float16 Ks[2][4096];
    __shared__ __align__(16) _Float16 Vs[2][4096];

    const int bid = blockIdx.x;
    int bh, qt, kh, tstart, tend;
    if (SPLIT) {
        const int swz0 = (bid & 7) * (NBLK2 / 8) + (bid >> 3);
        bh = swz0 / (NQT * 2);
        const int rr = swz0 % (NQT * 2);
        qt = rr >> 1;
        kh = rr & 1;
        tstart = kh ? 9 : 0;
        tend = kh ? NQT : 9;
    } else {
        const int swz0 = (bid & 7) * (NBLK / 8) + (bid >> 3);
        bh = swz0 / NQT;
        qt = swz0 % NQT;
        kh = 0;
        tstart = 0;
        tend = NQT;
    }
    const int h = bh % H_;
    const int tid = threadIdx.x;
    const int w = tid >> 6;
    const int lane = tid & 63;
    const int lq = lane & 15;
    const int g = lane >> 4;

    const size_t base = (size_t)bh * (N_ * D_);
    const float sg = LOG2E / (1.f + __expf(-GAMMA[h]));

    const int qrow = qt * 64 + w * 16 + lq;
    const bool qv = qrow < N_;

    half8 qf[2];
#pragma unroll
    for (int dh = 0; dh < 2; ++dh) {
        float4 t0 = make_float4(0, 0, 0, 0), t1 = t0;
        if (qv) {
            const float4* qp = (const float4*)(Q + base + (size_t)qrow * D_ + dh * 32 + g * 8);
            t0 = qp[0]; t1 = qp[1];
        }
        const float qs = 0.125f * LOG2E;
        half8 q8;
        q8[0] = (_Float16)(t0.x * qs); q8[1] = (_Float16)(t0.y * qs);
        q8[2] = (_Float16)(t0.z * qs); q8[3] = (_Float16)(t0.w * qs);
        q8[4] = (_Float16)(t1.x * qs); q8[5] = (_Float16)(t1.y * qs);
        q8[6] = (_Float16)(t1.z * qs); q8[7] = (_Float16)(t1.w * qs);
        qf[dh] = q8;
    }

    const bool qb = qv && (qrow >= 1);
    const float qbf = qb ? 1.f : 0.f;
    float aq = 0.f;
    int cq = 0;
    if (qb) {
        const int pq = qrow - 1;
        cq = (pq >> 5) * 63 + (pq & 31);
        aq = sg * MU[(size_t)bh * 2 * N_ + qrow];
    }
    int boff4[4];
#pragma unroll
    for (int kg = 0; kg < 4; ++kg) {
        const int pk0 = kg * 16 + g * 4 - 1;
        const int ck0 = (pk0 >> 5) * 63 + (pk0 & 31);
        boff4[kg] = (h * TBL_ + 1984 - cq + ck0) * 4 + tstart * 504;
    }
    const float* akb = akT + bh * 1088;
    const _Float16* kfb = Kf + (size_t)bh * NQT * 4096;
    const _Float16* vfb = Vf + (size_t)bh * NQT * 4096;

    f32x4 o[4];
    const f32x4 zz = {0.f, 0.f, 0.f, 0.f};
#pragma unroll
    for (int dg = 0; dg < 4; ++dg) o[dg] = zz;
    float m = 0.f, lsum = 0.f;

    {   // prologue: stage tile tstart
        const _Float16* kp = kfb + (size_t)tstart * 4096;
        const _Float16* vp = vfb + (size_t)tstart * 4096;
        _Float16* kd = &Ks[tstart & 1][0];
        _Float16* vd = &Vs[tstart & 1][0];
        stage16(kp + (2 * w + 0) * 512 + lane * 8, kd + (2 * w + 0) * 512);
        stage16(kp + (2 * w + 1) * 512 + lane * 8, kd + (2 * w + 1) * 512);
        stage16(vp + (2 * w + 0) * 512 + lane * 8, vd + (2 * w + 0) * 512);
        stage16(vp + (2 * w + 1) * 512 + lane * 8, vd + (2 * w + 1) * 512);
    }
    __syncthreads();

    const int pswz = (lq & 7) << 4;

    for (int t = tstart; t < tend; ++t) {
        const int buf = t & 1;
        const int kt0 = t * 64;
        char* plw = (char*)&Ks[buf][0] + w * 2048;  // aliases dead Ks after QK^T

        float bt16[16];
#pragma unroll
        for (int kg = 0; kg < 4; ++kg) {
            const int off = boff4[kg];
            if (kg & 1) {
                f32x4u f4 = *(const f32x4u*)(btb + off);
                bt16[kg * 4 + 0] = f4[0];
                bt16[kg * 4 + 1] = f4[1];
                bt16[kg * 4 + 2] = f4[2];
                bt16[kg * 4 + 3] = f4[3];
            } else {
                const bool cross = (g == 0);
                f32x4u f4 = *(const f32x4u*)(btb + off + (cross ? 128 : 0));
                const float s0v = *(const float*)(btb + off);
                bt16[kg * 4 + 0] = s0v;
                bt16[kg * 4 + 1] = cross ? f4[0] : f4[1];
                bt16[kg * 4 + 2] = cross ? f4[1] : f4[2];
                bt16[kg * 4 + 3] = cross ? f4[2] : f4[3];
            }
            boff4[kg] += 504;
        }
        f32x4 akq[4];
#pragma unroll
        for (int kg = 0; kg < 4; ++kg)
            akq[kg] = *(const f32x4*)(akb + kt0 + kg * 16 + g * 4);

        if (t + 1 < tend) {
            const _Float16* kn = kfb + (size_t)(t + 1) * 4096;
            const _Float16* vn = vfb + (size_t)(t + 1) * 4096;
            stage16(kn + (2 * w + 0) * 512 + lane * 8, &Ks[buf ^ 1][(2 * w + 0) * 512]);
            stage16(kn + (2 * w + 1) * 512 + lane * 8, &Ks[buf ^ 1][(2 * w + 1) * 512]);
            stage16(vn + (2 * w + 0) * 512 + lane * 8, &Vs[buf ^ 1][(2 * w + 0) * 512]);
            stage16(vn + (2 * w + 1) * 512 + lane * 8, &Vs[buf ^ 1][(2 * w + 1) * 512]);
        }

        const _Float16* ksl = &Ks[buf][lane * 8];
        f32x4 sa[4];
#pragma unroll
        for (int kg = 0; kg < 4; ++kg) {
            half8 a0 = *(const half8*)(ksl + (2 * kg + 0) * 512);
            half8 a1 = *(const half8*)(ksl + (2 * kg + 1) * 512);
            f32x4 z = zz;
            z = __builtin_amdgcn_mfma_f32_16x16x32_f16(a0, qf[0], z, 0, 0, 0);
            z = __builtin_amdgcn_mfma_f32_16x16x32_f16(a1, qf[1], z, 0, 0, 0);
            sa[kg] = z;
        }
        // all waves done reading Ks[buf]; no vmcnt drain (DMAs stay in flight)
        asm volatile("s_waitcnt lgkmcnt(0)" ::: "memory");
        __builtin_amdgcn_s_barrier();
        __builtin_amdgcn_sched_barrier(0);

        if (t == 0 && g == 0) bt16[0] = 0.f;  // k=0 column has no bias
        float s[16];
#pragma unroll
        for (int kg = 0; kg < 4; ++kg) {
#pragma unroll
            for (int r = 0; r < 4; ++r) {
                const int i = kg * 4 + r;
                s[i] = fmaf(fmaf(qbf, akq[kg][r], aq), bt16[i], sa[kg][r]);
            }
        }
        if (t == NQT - 1) {
#pragma unroll
            for (int kg = 0; kg < 4; ++kg)
#pragma unroll
                for (int r = 0; r < 4; ++r) {
                    const int i = kg * 4 + r;
                    if (1024 + kg * 16 + g * 4 + r >= N_) s[i] = -1e30f;
                }
        }

        float lmax = s[0];
#pragma unroll
        for (int i = 1; i < 16; ++i) lmax = fmaxf(lmax, s[i]);
        if (t == tstart) {
            float mt = fmaxf(lmax, __shfl_xor(lmax, 16));
            m = fmaxf(mt, __shfl_xor(mt, 32));
        } else if (!__all(lmax <= m + THR_)) {
            float mt = fmaxf(lmax, __shfl_xor(lmax, 16));
            mt = fmaxf(mt, __shfl_xor(mt, 32));
            const float mnew = fmaxf(m, mt);
            const float cc = EX2(m - mnew);
            m = mnew;
            lsum *= cc;
            float cc4[4];
#pragma unroll
            for (int r = 0; r < 4; ++r) cc4[r] = __shfl(cc, g * 4 + r);
#pragma unroll
            for (int dg = 0; dg < 4; ++dg)
#pragma unroll
                for (int r = 0; r < 4; ++r) o[dg][r] *= cc4[r];
        }
        float pv16[16];
        float ls0 = 0.f, ls1 = 0.f;
#pragma unroll
        for (int i = 0; i < 16; i += 2) {
            pv16[i] = EX2(s[i] - m);
            pv16[i + 1] = EX2(s[i + 1] - m);
            ls0 += pv16[i];
            ls1 += pv16[i + 1];
        }
        lsum += ls0 + ls1;

#pragma unroll
        for (int kg = 0; kg < 4; ++kg) {
            fp16x2 h0 = __builtin_amdgcn_cvt_pkrtz(pv16[kg * 4 + 0], pv16[kg * 4 + 1]);
            fp16x2 h1 = __builtin_amdgcn_cvt_pkrtz(pv16[kg * 4 + 2], pv16[kg * 4 + 3]);
            uint2 u = make_uint2(__builtin_bit_cast(uint32_t, h0),
                                 __builtin_bit_cast(uint32_t, h1));
            *(uint2*)(plw + lq * 128 + ((kg * 32 + g * 8) ^ pswz)) = u;
        }

#pragma unroll
        for (int khx = 0; khx < 2; ++khx) {
            half8 pa = *(const half8*)(plw + lq * 128 + ((khx * 64 + g * 16) ^ pswz));
#pragma unroll
            for (int dg = 0; dg < 4; ++dg) {
                half8 vb8 = *(const half8*)&Vs[buf][(khx * 4 + dg) * 512 + lane * 8];
                o[dg] = __builtin_amdgcn_mfma_f32_16x16x32_f16(pa, vb8, o[dg], 0, 0, 0);
            }
        }
        __syncthreads();
    }

    lsum += __shfl_xor(lsum, 16);
    lsum += __shfl_xor(lsum, 32);
    const float linv = 1.f / lsum;
    float li4[4];
#pragma unroll
    for (int r = 0; r < 4; ++r) li4[r] = __shfl(linv, g * 4 + r);
    if (SPLIT) {
        // normalized f16 partial + per-row (m, l)
        _Float16* op = Opart + (size_t)(bh * 2 + kh) * (1088 * 64);
#pragma unroll
        for (int dg = 0; dg < 4; ++dg) {
#pragma unroll
            for (int r = 0; r < 4; ++r) {
                const int qq = qt * 64 + w * 16 + g * 4 + r;
                op[(size_t)qq * 64 + dg * 16 + lq] = (_Float16)(o[dg][r] * li4[r]);
            }
        }
        if (g == 0 && qv) {
            float2* mlp = (float2*)mlb + (size_t)(bh * 2 + kh) * 1088 + qrow;
            *mlp = make_float2(m, lsum);
        }
    } else {
#pragma unroll
        for (int dg = 0; dg < 4; ++dg) {
#pragma unroll
            for (int r = 0; r < 4; ++r) {
                const int qq = qt * 64 + w * 16 + g * 4 + r;
                if (qq < N_) OUT[base + (size_t)qq * D_ + dg * 16 + lq] = o[dg][r] * li4[r];
            }
        }
    }
}

// ---------------- merge: combine the two k-half partials per row
__global__ __launch_bounds__(256) void merge(const _Float16* __restrict__ Opart,
                                             const float* __restrict__ mlb,
                                             float* __restrict__ OUT) {
    const int idx = blockIdx.x * 256 + threadIdx.x;
    if (idx >= B_ * H_ * N_ * 8) return;
    const int d8 = (idx & 7) * 8;
    const int rg = idx >> 3;
    const int bh = rg / N_;
    const int qq = rg % N_;
    const float2 ml0 = ((const float2*)mlb)[(size_t)(bh * 2 + 0) * 1088 + qq];
    const float2 ml1 = ((const float2*)mlb)[(size_t)(bh * 2 + 1) * 1088 + qq];
    const float M = fmaxf(ml0.x, ml1.x);
    const float w0 = ml0.y * EX2(ml0.x - M);
    const float w1 = ml1.y * EX2(ml1.x - M);
    const float inv = 1.f / (w0 + w1);
    const float c0 = w0 * inv, c1 = w1 * inv;
    const half8 o0 = *(const half8*)(Opart + (size_t)(bh * 2 + 0) * (1088 * 64) +
                                     (size_t)qq * 64 + d8);
    const half8 o1 = *(const half8*)(Opart + (size_t)(bh * 2 + 1) * (1088 * 64) +
                                     (size_t)qq * 64 + d8);
    float* op = OUT + (size_t)bh * (N_ * D_) + (size_t)qq * 64 + d8;
    float4 r0, r1;
    r0.x = fmaf(c0, (float)o0[0], c1 * (float)o1[0]);
    r0.y = fmaf(c0, (float)o0[1], c1 * (float)o1[1]);
    r0.z = fmaf(c0, (float)o0[2], c1 * (float)o1[2]);
    r0.w = fmaf(c0, (float)o0[3], c1 * (float)o1[3]);
    r1.x = fmaf(c0, (float)o0[4], c1 * (float)o1[4]);
    r1.y = fmaf(c0, (float)o0[5], c1 * (float)o1[5]);
    r1.z = fmaf(c0, (float)o0[6], c1 * (float)o1[6]);
    r1.w = fmaf(c0, (float)o0[7], c1 * (float)o1[7]);
    ((float4*)op)[0] = r0;
    ((float4*)op)[1] = r1;
}

extern "C" void kernel_launch(void* const* d_in, const int* in_sizes, int n_in,
                              void* d_out, int out_size, void* d_ws, size_t ws_size,
                              hipStream_t stream) {
    const float* q = (const float*)d_in[0];
    const float* k = (const float*)d_in[1];
    const float* v = (const float*)d_in[2];
    const float* mu = (const float*)d_in[3];
    const float* w1 = (const float*)d_in[4];
    const float* b1 = (const float*)d_in[5];
    const float* w2 = (const float*)d_in[6];
    const float* gamma = (const float*)d_in[7];
    const float* rel = (const float*)d_in[8];
    // d_in[9] = idx_table: reconstructed analytically, never read.

    char* ws = (char*)d_ws;
    float* akT = (float*)(ws + AKT_OFF);
    float* btR = (float*)(ws + BTR_OFF);
    _Float16* Kf = (_Float16*)(ws + KF_OFF);
    _Float16* Vf = (_Float16*)(ws + VF_OFF);
    _Float16* Opart = (_Float16*)(ws + OP_OFF);
    float* mlb = (float*)(ws + ML_OFF);

    prep<<<NBLK + (TBL_ + 255) / 256, 256, 0, stream>>>(k, v, mu, gamma, rel, w1, b1, w2,
                                                        Kf, Vf, akT, btR);
    if (ws_size >= WS_NEED) {
        flex_attn<1><<<NBLK2, 256, 0, stream>>>(q, Kf, Vf, mu, gamma, ws + BTR_OFF, akT,
                                                Opart, mlb, (float*)d_out);
        merge<<<(B_ * H_ * N_ * 8 + 255) / 256, 256, 0, stream>>>(Opart, mlb,
                                                                  (float*)d_out);
    } else {
        flex_attn<0><<<NBLK, 256, 0, stream>>>(q, Kf, Vf, mu, gamma, ws + BTR_OFF, akT,
                                               Opart, mlb, (float*)d_out);
    }
}